// Round 8
// baseline (365.049 us; speedup 1.0000x reference)
//
#include <hip/hip_runtime.h>

// EPN_flax, round 8: P/Q fp32 per-atom projections; E-term + layer2 on f16
// MFMA with k-permuted W1 fragments (register-only layer1->layer2 handoff);
// 1/16 pre-scale; b2 cancels. New this round:
//  - C-init: layer1 acc starts at Pi+Qj (u) / Pj+Qi (v); layer2 acc starts at
//    b1/16 (epilogue fma -> bare max; 16x fold into precomputed 16*W2).
//  - K=16 layer-1 MFMA (all lanes hold real e-features; no act-lane masking).
//  - 2-way i-interleave per wave: two independent dependency chains; shared
//    Qj/Pj/W1/b1/w2 LDS reads. __launch_bounds__(256,4).

constexpr int Nn = 1024;

typedef _Float16 half4 __attribute__((ext_vector_type(4)));
typedef _Float16 half8 __attribute__((ext_vector_type(8)));
typedef __fp16   fp16x2 __attribute__((ext_vector_type(2)));
typedef float    f32x4 __attribute__((ext_vector_type(4)));
typedef unsigned int uint2v __attribute__((ext_vector_type(2)));
typedef unsigned int uint4v __attribute__((ext_vector_type(4)));

#define MFMAH32(A, B, C) __builtin_amdgcn_mfma_f32_16x16x32_f16(A, B, C, 0, 0, 0)

#if __has_builtin(__builtin_amdgcn_mfma_f32_16x16x16f16)
__device__ inline f32x4 mfma16(half4 a, half4 b, f32x4 c) {
    return __builtin_amdgcn_mfma_f32_16x16x16f16(a, b, c, 0, 0, 0);
}
#else
__device__ inline f32x4 mfma16(half4 a, half4 b, f32x4 c) {
    // zero-padded fallback: features live in slots j<4 of each quad's k-range
    half8 a8 = {a[0], a[1], a[2], a[3], (_Float16)0, (_Float16)0, (_Float16)0, (_Float16)0};
    half8 b8 = {b[0], b[1], b[2], b[3], (_Float16)0, (_Float16)0, (_Float16)0, (_Float16)0};
    return MFMAH32(a8, b8, c);
}
#endif

__device__ inline unsigned int pkrtz(float a, float b) {
    fp16x2 r = __builtin_amdgcn_cvt_pkrtz(a, b);
    return __builtin_bit_cast(unsigned int, r);
}
__device__ inline f32x4 max0(f32x4 a) {
    f32x4 z = {0.f, 0.f, 0.f, 0.f};
    return __builtin_elementwise_max(a, z);
}

// ---- setup: weight fragments (3 timesteps), scaled b1/W2, q->qout copy ----
__global__ __launch_bounds__(256) void epn_frag_kernel(
    const float* __restrict__ W0,   // [3][80][64]
    const float* __restrict__ W1,   // [3][64][64]
    const float* __restrict__ b1,   // [3][64]
    const float* __restrict__ W2,   // [3][64]
    const float* __restrict__ qin,
    uint2v* __restrict__ fw0e,      // [3][4][64]  K=16 A-frags (4 halfs)
    uint4*  __restrict__ fw1,       // [3][8][64]  sigma-permuted K=32 A-frags
    float*  __restrict__ b1s,       // [3][64] = b1/16
    float*  __restrict__ w2s,       // [3][64] = 16*W2
    float*  __restrict__ qout)
{
    const int idx = blockIdx.x * 256 + threadIdx.x;   // grid 11 -> 2816
    if (idx < 768) {                                  // fw0e: (ts, t, lane)
        int lane = idx & 63, t = (idx >> 6) & 3, ts = idx >> 8;
        int nl = lane & 15, qd = lane >> 4;
        float v[4];
        #pragma unroll
        for (int j = 0; j < 4; ++j)
            v[j] = W0[ts * 80 * 64 + (64 + qd * 4 + j) * 64 + t * 16 + nl] * 0.0625f;
        uint2v p = {pkrtz(v[0], v[1]), pkrtz(v[2], v[3])};
        fw0e[idx] = p;
    } else if (idx < 2304) {                          // fw1: (ts, sp, t2, lane)
        int i2 = idx - 768;
        int lane = i2 & 63, t2 = (i2 >> 6) & 3, sp = (i2 >> 8) & 1, ts = i2 >> 9;
        int nl = lane & 15, qd = lane >> 4;
        float v[8];
        #pragma unroll
        for (int j = 0; j < 8; ++j) {
            int k = (2 * (j >> 2) + sp) * 16 + qd * 4 + (j & 3);   // sigma-permuted k
            v[j] = W1[ts * 64 * 64 + k * 64 + t2 * 16 + nl];
        }
        uint4 p;
        p.x = pkrtz(v[0], v[1]); p.y = pkrtz(v[2], v[3]);
        p.z = pkrtz(v[4], v[5]); p.w = pkrtz(v[6], v[7]);
        fw1[(ts * 8 + sp * 4 + t2) * 64 + lane] = p;
    } else if (idx < 2496) {                          // b1s / w2s: (ts, m)
        int i2 = idx - 2304;
        b1s[i2] = b1[i2] * 0.0625f;
        w2s[i2] = W2[i2] * 16.f;
    } else if (idx < 2752) {                          // q -> qout (float4 x 256)
        int i4 = idx - 2496;
        *(float4*)&qout[i4 * 4] = *(const float4*)&qin[i4 * 4];
    }
}

// ---------------- per-timestep projection: P,Q (fp32, pre-scaled 1/16) ----------------
__global__ __launch_bounds__(256) void epn_proj_kernel(
    const float* __restrict__ h, const float* __restrict__ qcur,
    const float* __restrict__ W0, const float* __restrict__ b0,
    float* __restrict__ P, float* __restrict__ Q)
{
    __shared__ float sa[4][32];
    const int tid = threadIdx.x;
    const int base = blockIdx.x * 4;
    if (tid < 128) {
        int la = tid >> 5, c = tid & 31, atom = base + la;
        sa[la][c] = (c < 31) ? h[atom * 31 + c] : qcur[atom];
    }
    __syncthreads();
    const int la = tid >> 6, m = tid & 63, atom = base + la;
    float accP = b0[m], accQ = 0.f;
    #pragma unroll
    for (int c = 0; c < 32; ++c) {
        float av = sa[la][c];
        accP = fmaf(av, W0[c * 64 + m], accP);
        accQ = fmaf(av, W0[(32 + c) * 64 + m], accQ);
    }
    P[atom * 64 + m] = accP * 0.0625f;
    Q[atom * 64 + m] = accQ * 0.0625f;
}

// ---------------- main pair kernel ----------------
__global__ __launch_bounds__(256, 4) void epn_main_kernel(
    const float* __restrict__ e, const float* __restrict__ mask,
    const float* __restrict__ Pg, const float* __restrict__ Qg,
    const uint2v* __restrict__ fragW0e,  // [4][64]
    const uint4*  __restrict__ fragW1,   // [8][64] (sp*4+t2 major)
    const float* __restrict__ b1s, const float* __restrict__ w2s,
    float* __restrict__ qout)
{
    __shared__ float sP[32][68];           // rows 0-15: i-atoms, 16-31: j-atoms
    __shared__ float sQ[32][68];
    __shared__ __align__(16) uint4 sW1[8][64];
    __shared__ float sb1[64];
    __shared__ float sw2[64];

    const int tid  = threadIdx.x;
    const int lane = tid & 63;
    const int wv   = tid >> 6;
    const int nl   = lane & 15;
    const int qd   = lane >> 4;
    const int i0   = blockIdx.y * 16;
    const int j0   = blockIdx.x * 16;

    // stage P/Q (coalesced b128 global -> LDS)
    for (int idx = tid; idx < 512; idx += 256) {
        int r = idx >> 4, c4 = (idx & 15) * 4;
        int atom = (r < 16) ? (i0 + r) : (j0 + r - 16);
        *(float4*)&sP[r][c4] = *(const float4*)&Pg[atom * 64 + c4];
        *(float4*)&sQ[r][c4] = *(const float4*)&Qg[atom * 64 + c4];
    }
    // stage W1 fragments + scaled b1/w2
    for (int idx = tid; idx < 512; idx += 256)
        sW1[idx >> 6][idx & 63] = fragW1[idx];
    if (tid < 64) { sb1[tid] = b1s[tid]; sw2[tid] = w2s[tid]; }

    // layer-1 weight A-frags in registers (K=16: 2 regs each)
    uint2v Aw0e[4];
    #pragma unroll
    for (int t = 0; t < 4; ++t) Aw0e[t] = fragW0e[t * 64 + lane];

    // prefetch gp=0: e (one float4 per lane per chain) + masks
    float4 eP[2]; float mP[2];
    #pragma unroll
    for (int c = 0; c < 2; ++c) {
        int il = wv * 4 + c;
        eP[c] = *(const float4*)(e + ((size_t)(i0 + il) * Nn + (j0 + nl)) * 16 + qd * 4);
        mP[c] = mask[(size_t)(i0 + il) * Nn + j0 + nl];
    }

    __syncthreads();

    #pragma unroll
    for (int gp = 0; gp < 2; ++gp) {
        const int base_il = wv * 4 + gp * 2;
        float4 ec[2] = {eP[0], eP[1]};
        float  mc[2] = {mP[0], mP[1]};
        if (gp == 0) {   // software prefetch next iteration
            #pragma unroll
            for (int c = 0; c < 2; ++c) {
                int il = wv * 4 + 2 + c;
                eP[c] = *(const float4*)(e + ((size_t)(i0 + il) * Nn + (j0 + nl)) * 16 + qd * 4);
                mP[c] = mask[(size_t)(i0 + il) * Nn + j0 + nl];
            }
        }

        half4 Be[2];
        #pragma unroll
        for (int c = 0; c < 2; ++c) {
            uint2v p = {pkrtz(ec[c].x, ec[c].y), pkrtz(ec[c].z, ec[c].w)};
            Be[c] = __builtin_bit_cast(half4, p);
        }

        // layer 1 (C-init = Pi+Qj / Pj+Qi) -> relu -> pack into layer-2 B-frags
        uint4v bu[2][2], bv[2][2];   // [chain][sp]
        #pragma unroll
        for (int t = 0; t < 4; ++t) {
            const int off = t * 16 + qd * 4;
            f32x4 Qj = *(const f32x4*)&sQ[16 + nl][off];   // shared across chains
            f32x4 Pj = *(const f32x4*)&sP[16 + nl][off];
            half4 aw = __builtin_bit_cast(half4, Aw0e[t]);
            const int sp = t & 1, b = (t >> 1) * 2;
            #pragma unroll
            for (int c = 0; c < 2; ++c) {
                const int il = base_il + c;
                f32x4 Pi = *(const f32x4*)&sP[il][off];    // wave-uniform broadcast
                f32x4 Qi = *(const f32x4*)&sQ[il][off];
                f32x4 Eu = max0(mfma16(aw, Be[c], Pi + Qj));
                f32x4 Ev = max0(mfma16(aw, Be[c], Pj + Qi));
                bu[c][sp][b]     = pkrtz(Eu[0], Eu[1]);
                bu[c][sp][b + 1] = pkrtz(Eu[2], Eu[3]);
                bv[c][sp][b]     = pkrtz(Ev[0], Ev[1]);
                bv[c][sp][b + 1] = pkrtz(Ev[2], Ev[3]);
            }
        }

        // layer 2 (C-init = b1/16) + epilogue (16x folded into w2s)
        f32x4 s4[2] = {{0.f, 0.f, 0.f, 0.f}, {0.f, 0.f, 0.f, 0.f}};
        #pragma unroll
        for (int t2 = 0; t2 < 4; ++t2) {
            f32x4 binit = *(const f32x4*)&sb1[t2 * 16 + qd * 4];
            f32x4 w2q   = *(const f32x4*)&sw2[t2 * 16 + qd * 4];
            half8 w1a = *(const half8*)&sW1[t2][lane];       // sp=0
            half8 w1b = *(const half8*)&sW1[4 + t2][lane];   // sp=1
            #pragma unroll
            for (int c = 0; c < 2; ++c) {
                f32x4 x = MFMAH32(w1a, __builtin_bit_cast(half8, bu[c][0]), binit);
                x = MFMAH32(w1b, __builtin_bit_cast(half8, bu[c][1]), x);
                f32x4 y = MFMAH32(w1a, __builtin_bit_cast(half8, bv[c][0]), binit);
                y = MFMAH32(w1b, __builtin_bit_cast(half8, bv[c][1]), y);
                s4[c] += (max0(x) - max0(y)) * w2q;
            }
        }

        // mask + reduce + atomic, per chain (independent shuffle chains)
        #pragma unroll
        for (int c = 0; c < 2; ++c) {
            float s = ((s4[c][0] + s4[c][1]) + (s4[c][2] + s4[c][3])) * mc[c];
            s += __shfl_xor(s, 1);
            s += __shfl_xor(s, 2);
            s += __shfl_xor(s, 4);
            s += __shfl_xor(s, 8);
            s += __shfl_xor(s, 16);
            s += __shfl_xor(s, 32);
            if (lane == 0) atomicAdd(&qout[i0 + base_il + c], s);
        }
    }
}

extern "C" void kernel_launch(void* const* d_in, const int* in_sizes, int n_in,
                              void* d_out, int out_size, void* d_ws, size_t ws_size,
                              hipStream_t stream) {
    const float* h    = (const float*)d_in[0];
    const float* e    = (const float*)d_in[1];
    const float* q    = (const float*)d_in[2];
    const float* mask = (const float*)d_in[3];
    const float* W0   = (const float*)d_in[5];
    const float* b0   = (const float*)d_in[6];
    const float* W1   = (const float*)d_in[7];
    const float* b1   = (const float*)d_in[8];
    const float* W2   = (const float*)d_in[9];
    // d_in[10] = b2 cancels in the antisymmetrization

    float* qout = (float*)d_out;
    char*  ws   = (char*)d_ws;
    float*  Pws  = (float*)(ws);                        // 256 KB
    float*  Qws  = (float*)(ws + 256 * 1024);           // 256 KB
    uint2v* fw0e = (uint2v*)(ws + 512 * 1024);          // 6 KB
    uint4*  fw1  = (uint4*)(ws + 512 * 1024 + 6144);    // 24 KB
    float*  b1s  = (float*)(ws + 512 * 1024 + 30720);   // 768 B
    float*  w2s  = (float*)(ws + 512 * 1024 + 31488);   // 768 B

    epn_frag_kernel<<<11, 256, 0, stream>>>(W0, W1, b1, W2, q, fw0e, fw1, b1s, w2s, qout);
    for (int t = 0; t < 3; ++t) {
        epn_proj_kernel<<<256, 256, 0, stream>>>(h, qout, W0 + t * 80 * 64, b0 + t * 64,
                                                 Pws, Qws);
        epn_main_kernel<<<dim3(64, 64), 256, 0, stream>>>(
            e, mask, Pws, Qws,
            fw0e + (size_t)t * 4 * 64, fw1 + (size_t)t * 8 * 64,
            b1s + t * 64, w2s + t * 64, qout);
    }
}

// Round 9
// 235.920 us; speedup vs baseline: 1.5473x; 1.5473x over previous
//
#include <hip/hip_runtime.h>

// EPN_flax, round 9: P/Q fp32 per-atom projections; E-term (K=16 f16 MFMA,
// C-init = Pi+Qj / Pj+Qi) + layer2 (K=32 f16 MFMA, C-init = b1/16, k-permuted
// W1 frags -> register-only handoff); 1/16 pre-scale; b2 cancels.
// New this round: grid = 1024 blocks (4/CU, ALL co-resident -> no ramp/drain);
// each block walks 4 j-tiles, re-staging j-side P/Q via register-buffered
// global loads issued a full step early (2-barrier swap). Single chain per
// group (round-8 interleave spilled: WRITE_SIZE 2->13 MB).

constexpr int Nn = 1024;

typedef _Float16 half4 __attribute__((ext_vector_type(4)));
typedef _Float16 half8 __attribute__((ext_vector_type(8)));
typedef __fp16   fp16x2 __attribute__((ext_vector_type(2)));
typedef float    f32x4 __attribute__((ext_vector_type(4)));
typedef unsigned int uint2v __attribute__((ext_vector_type(2)));
typedef unsigned int uint4v __attribute__((ext_vector_type(4)));

#define MFMAH32(A, B, C) __builtin_amdgcn_mfma_f32_16x16x32_f16(A, B, C, 0, 0, 0)

#if __has_builtin(__builtin_amdgcn_mfma_f32_16x16x16f16)
__device__ inline f32x4 mfma16(half4 a, half4 b, f32x4 c) {
    return __builtin_amdgcn_mfma_f32_16x16x16f16(a, b, c, 0, 0, 0);
}
#else
__device__ inline f32x4 mfma16(half4 a, half4 b, f32x4 c) {
    // zero-padded fallback: features in slots j<4 of each quad's k-range
    half8 a8 = {a[0], a[1], a[2], a[3], (_Float16)0, (_Float16)0, (_Float16)0, (_Float16)0};
    half8 b8 = {b[0], b[1], b[2], b[3], (_Float16)0, (_Float16)0, (_Float16)0, (_Float16)0};
    return MFMAH32(a8, b8, c);
}
#endif

__device__ inline unsigned int pkrtz(float a, float b) {
    fp16x2 r = __builtin_amdgcn_cvt_pkrtz(a, b);
    return __builtin_bit_cast(unsigned int, r);
}
__device__ inline f32x4 max0(f32x4 a) {
    f32x4 z = {0.f, 0.f, 0.f, 0.f};
    return __builtin_elementwise_max(a, z);
}

// ---- setup: weight fragments (3 timesteps), scaled b1/W2, q->qout copy ----
__global__ __launch_bounds__(256) void epn_frag_kernel(
    const float* __restrict__ W0,   // [3][80][64]
    const float* __restrict__ W1,   // [3][64][64]
    const float* __restrict__ b1,   // [3][64]
    const float* __restrict__ W2,   // [3][64]
    const float* __restrict__ qin,
    uint2v* __restrict__ fw0e,      // [3][4][64]  K=16 A-frags
    uint4*  __restrict__ fw1,       // [3][8][64]  sigma-permuted K=32 A-frags
    float*  __restrict__ b1s,       // [3][64] = b1/16
    float*  __restrict__ w2s,       // [3][64] = 16*W2
    float*  __restrict__ qout)
{
    const int idx = blockIdx.x * 256 + threadIdx.x;   // grid 11 -> 2816
    if (idx < 768) {                                  // fw0e: (ts, t, lane)
        int lane = idx & 63, t = (idx >> 6) & 3, ts = idx >> 8;
        int nl = lane & 15, qd = lane >> 4;
        float v[4];
        #pragma unroll
        for (int j = 0; j < 4; ++j)
            v[j] = W0[ts * 80 * 64 + (64 + qd * 4 + j) * 64 + t * 16 + nl] * 0.0625f;
        uint2v p = {pkrtz(v[0], v[1]), pkrtz(v[2], v[3])};
        fw0e[idx] = p;
    } else if (idx < 2304) {                          // fw1: (ts, sp, t2, lane)
        int i2 = idx - 768;
        int lane = i2 & 63, t2 = (i2 >> 6) & 3, sp = (i2 >> 8) & 1, ts = i2 >> 9;
        int nl = lane & 15, qd = lane >> 4;
        float v[8];
        #pragma unroll
        for (int j = 0; j < 8; ++j) {
            int k = (2 * (j >> 2) + sp) * 16 + qd * 4 + (j & 3);   // sigma-permuted k
            v[j] = W1[ts * 64 * 64 + k * 64 + t2 * 16 + nl];
        }
        uint4 p;
        p.x = pkrtz(v[0], v[1]); p.y = pkrtz(v[2], v[3]);
        p.z = pkrtz(v[4], v[5]); p.w = pkrtz(v[6], v[7]);
        fw1[(ts * 8 + sp * 4 + t2) * 64 + lane] = p;
    } else if (idx < 2496) {                          // b1s / w2s
        int i2 = idx - 2304;
        b1s[i2] = b1[i2] * 0.0625f;
        w2s[i2] = W2[i2] * 16.f;
    } else if (idx < 2752) {                          // q -> qout
        int i4 = idx - 2496;
        *(float4*)&qout[i4 * 4] = *(const float4*)&qin[i4 * 4];
    }
}

// ---------------- per-timestep projection: P,Q (fp32, pre-scaled 1/16) ----------------
__global__ __launch_bounds__(256) void epn_proj_kernel(
    const float* __restrict__ h, const float* __restrict__ qcur,
    const float* __restrict__ W0, const float* __restrict__ b0,
    float* __restrict__ P, float* __restrict__ Q)
{
    __shared__ float sa[4][32];
    const int tid = threadIdx.x;
    const int base = blockIdx.x * 4;
    if (tid < 128) {
        int la = tid >> 5, c = tid & 31, atom = base + la;
        sa[la][c] = (c < 31) ? h[atom * 31 + c] : qcur[atom];
    }
    __syncthreads();
    const int la = tid >> 6, m = tid & 63, atom = base + la;
    float accP = b0[m], accQ = 0.f;
    #pragma unroll
    for (int c = 0; c < 32; ++c) {
        float av = sa[la][c];
        accP = fmaf(av, W0[c * 64 + m], accP);
        accQ = fmaf(av, W0[(32 + c) * 64 + m], accQ);
    }
    P[atom * 64 + m] = accP * 0.0625f;
    Q[atom * 64 + m] = accQ * 0.0625f;
}

// ---------------- main pair kernel: grid dim3(16, 64) ----------------
__global__ __launch_bounds__(256, 4) void epn_main_kernel(
    const float* __restrict__ e, const float* __restrict__ mask,
    const float* __restrict__ Pg, const float* __restrict__ Qg,
    const uint2v* __restrict__ fragW0e,  // [4][64]
    const uint4*  __restrict__ fragW1,   // [8][64] (sp*4+t2 major)
    const float* __restrict__ b1s, const float* __restrict__ w2s,
    float* __restrict__ qout)
{
    __shared__ float sPi[16][68], sQi[16][68];   // i-side, staged once
    __shared__ float sPj[16][68], sQj[16][68];   // j-side, re-staged per step
    __shared__ float sb1[64], sw2[64];

    const int tid  = threadIdx.x;
    const int lane = tid & 63;
    const int wv   = tid >> 6;
    const int nl   = lane & 15;
    const int qd   = lane >> 4;
    const int i0   = blockIdx.y * 16;    // 64 i-tiles
    const int jb   = blockIdx.x * 64;    // 16 j-blocks, each walks 4 j-tiles

    // stage i-side P/Q + j-side step 0 (one float4 per thread per array)
    const int sr = tid >> 4, sc4 = (tid & 15) * 4;
    *(float4*)&sPi[sr][sc4] = *(const float4*)&Pg[(i0 + sr) * 64 + sc4];
    *(float4*)&sQi[sr][sc4] = *(const float4*)&Qg[(i0 + sr) * 64 + sc4];
    *(float4*)&sPj[sr][sc4] = *(const float4*)&Pg[(jb + sr) * 64 + sc4];
    *(float4*)&sQj[sr][sc4] = *(const float4*)&Qg[(jb + sr) * 64 + sc4];
    if (tid < 64) { sb1[tid] = b1s[tid]; sw2[tid] = w2s[tid]; }

    // weight frags in registers
    uint2v Aw0e[4];
    #pragma unroll
    for (int t = 0; t < 4; ++t) Aw0e[t] = fragW0e[t * 64 + lane];
    uint4 w1r[8];
    #pragma unroll
    for (int i = 0; i < 8; ++i) w1r[i] = fragW1[i * 64 + lane];

    // e/mask prefetch for gs=0
    float4 eP = *(const float4*)(e + ((size_t)(i0 + wv * 4) * Nn + (jb + nl)) * 16 + qd * 4);
    float  mP = mask[(size_t)(i0 + wv * 4) * Nn + jb + nl];

    __syncthreads();

    for (int st = 0; st < 4; ++st) {
        // issue next step's j-side loads now (land during compute)
        float4 pjr, qjr;
        if (st < 3) {
            int jatom = jb + (st + 1) * 16 + sr;
            pjr = *(const float4*)&Pg[jatom * 64 + sc4];
            qjr = *(const float4*)&Qg[jatom * 64 + sc4];
        }

        #pragma unroll
        for (int g = 0; g < 4; ++g) {
            const int il = wv * 4 + g;
            float4 ec = eP; float mc = mP;
            const int gs = st * 4 + g;
            if (gs < 15) {   // prefetch next (step, group)
                int ngs = gs + 1, nst = ngs >> 2, ng = ngs & 3;
                int nil = wv * 4 + ng;
                eP = *(const float4*)(e + ((size_t)(i0 + nil) * Nn + (jb + nst * 16 + nl)) * 16 + qd * 4);
                mP = mask[(size_t)(i0 + nil) * Nn + jb + nst * 16 + nl];
            }

            uint2v ep = {pkrtz(ec.x, ec.y), pkrtz(ec.z, ec.w)};
            half4 Be = __builtin_bit_cast(half4, ep);

            // layer 1 (C-init = Pi+Qj / Pj+Qi) -> relu -> pack into L2 B-frags
            uint4v bu[2], bv[2];
            #pragma unroll
            for (int t = 0; t < 4; ++t) {
                const int off = t * 16 + qd * 4;
                f32x4 Pi = *(const f32x4*)&sPi[il][off];    // wave-uniform broadcast
                f32x4 Qi = *(const f32x4*)&sQi[il][off];
                f32x4 Qj = *(const f32x4*)&sQj[nl][off];    // per-lane
                f32x4 Pj = *(const f32x4*)&sPj[nl][off];
                half4 aw = __builtin_bit_cast(half4, Aw0e[t]);
                f32x4 Eu = max0(mfma16(aw, Be, Pi + Qj));
                f32x4 Ev = max0(mfma16(aw, Be, Pj + Qi));
                const int sp = t & 1, b = (t >> 1) * 2;
                bu[sp][b]     = pkrtz(Eu[0], Eu[1]);
                bu[sp][b + 1] = pkrtz(Eu[2], Eu[3]);
                bv[sp][b]     = pkrtz(Ev[0], Ev[1]);
                bv[sp][b + 1] = pkrtz(Ev[2], Ev[3]);
            }

            // layer 2 (C-init = b1/16) + epilogue (16x folded into w2s)
            f32x4 s4 = {0.f, 0.f, 0.f, 0.f};
            #pragma unroll
            for (int t2 = 0; t2 < 4; ++t2) {
                f32x4 binit = *(const f32x4*)&sb1[t2 * 16 + qd * 4];
                f32x4 w2q   = *(const f32x4*)&sw2[t2 * 16 + qd * 4];
                half8 w1a = __builtin_bit_cast(half8, w1r[t2]);
                half8 w1b = __builtin_bit_cast(half8, w1r[4 + t2]);
                f32x4 x = MFMAH32(w1a, __builtin_bit_cast(half8, bu[0]), binit);
                x = MFMAH32(w1b, __builtin_bit_cast(half8, bu[1]), x);
                f32x4 y = MFMAH32(w1a, __builtin_bit_cast(half8, bv[0]), binit);
                y = MFMAH32(w1b, __builtin_bit_cast(half8, bv[1]), y);
                s4 += (max0(x) - max0(y)) * w2q;
            }

            float s = ((s4[0] + s4[1]) + (s4[2] + s4[3])) * mc;
            s += __shfl_xor(s, 1);
            s += __shfl_xor(s, 2);
            s += __shfl_xor(s, 4);
            s += __shfl_xor(s, 8);
            s += __shfl_xor(s, 16);
            s += __shfl_xor(s, 32);
            if (lane == 0) atomicAdd(&qout[i0 + il], s);
        }

        if (st < 3) {   // swap in next j-tile
            __syncthreads();
            *(float4*)&sPj[sr][sc4] = pjr;
            *(float4*)&sQj[sr][sc4] = qjr;
            __syncthreads();
        }
    }
}

extern "C" void kernel_launch(void* const* d_in, const int* in_sizes, int n_in,
                              void* d_out, int out_size, void* d_ws, size_t ws_size,
                              hipStream_t stream) {
    const float* h    = (const float*)d_in[0];
    const float* e    = (const float*)d_in[1];
    const float* q    = (const float*)d_in[2];
    const float* mask = (const float*)d_in[3];
    const float* W0   = (const float*)d_in[5];
    const float* b0   = (const float*)d_in[6];
    const float* W1   = (const float*)d_in[7];
    const float* b1   = (const float*)d_in[8];
    const float* W2   = (const float*)d_in[9];
    // d_in[10] = b2 cancels in the antisymmetrization

    float* qout = (float*)d_out;
    char*  ws   = (char*)d_ws;
    float*  Pws  = (float*)(ws);                        // 256 KB
    float*  Qws  = (float*)(ws + 256 * 1024);           // 256 KB
    uint2v* fw0e = (uint2v*)(ws + 512 * 1024);          // 6 KB
    uint4*  fw1  = (uint4*)(ws + 512 * 1024 + 6144);    // 24 KB
    float*  b1s  = (float*)(ws + 512 * 1024 + 30720);   // 768 B
    float*  w2s  = (float*)(ws + 512 * 1024 + 31488);   // 768 B

    epn_frag_kernel<<<11, 256, 0, stream>>>(W0, W1, b1, W2, q, fw0e, fw1, b1s, w2s, qout);
    for (int t = 0; t < 3; ++t) {
        epn_proj_kernel<<<256, 256, 0, stream>>>(h, qout, W0 + t * 80 * 64, b0 + t * 64,
                                                 Pws, Qws);
        epn_main_kernel<<<dim3(16, 64), 256, 0, stream>>>(
            e, mask, Pws, Qws,
            fw0e + (size_t)t * 4 * 64, fw1 + (size_t)t * 8 * 64,
            b1s + t * 64, w2s + t * 64, qout);
    }
}